// Round 5
// baseline (149.117 us; speedup 1.0000x reference)
//
#include <hip/hip_runtime.h>

// ChebyshevAdditiveAngularMargin — HBM/fabric-bound elementwise op.
//   cosine = clip(outputs, -1+1e-7, 1-1e-7)
//   phi    = clenshaw(cosine, coeffs)            (Chebyshev, degree 30)
//   phi    = cosine > TH ? phi : cosine - MM
//   out    = 30 * (targets*phi + (1-targets)*cosine)   (targets one-hot)
//
// Traffic: outputs 256MB (HBM) + targets 256MB (L3-resident, measured) +
// write 256MB (HBM). HBM floor ~81us at copy efficiency; target ~95-105us.
// Ladder: R1 grid-stride 162us -> R4 static grid, 4xfloat4/thread, batched
// loads 145us. R5: kPerThread=8 (16 outstanding dwordx4/thread, o/t pairs
// interleaved for incremental vmcnt waits) — trade TLP for ILP; we are
// latency-bound (VALUBusy 6.5%, VGPR 20, HBM 3.6 of 6.3 TB/s).

namespace {

typedef float f32x4 __attribute__((ext_vector_type(4)));

constexpr float kClipLo = -0.9999999f;   // -1 + 1e-7 rounded to f32
constexpr float kClipHi =  0.9999999f;   //  1 - 1e-7 rounded to f32
constexpr float kTH     = -0.98006657784124163f;  // cos(pi - 0.2)
constexpr float kMM     =  0.039733866159012243f; // sin(pi - 0.2) * 0.2
constexpr float kSCALE  = 30.0f;
constexpr int   kDegree = 30;            // 31 coefficients
constexpr int   kPerThread = 8;          // float4s per thread per array

__device__ __forceinline__ float clenshaw_phi(float x, const float* __restrict__ coeffs) {
    // b_k = c_k + 2x*b_{k+1} - b_{k+2}, k = DEGREE..0;  f(x) = b_0 - x*b_1
    const float x2 = 2.0f * x;
    float b1 = 0.0f, b2 = 0.0f;
#pragma unroll
    for (int k = kDegree; k >= 0; --k) {
        float b = coeffs[k] + x2 * b1 - b2;
        b2 = b1;
        b1 = b;
    }
    return b1 - b2 * x;
}

__device__ __forceinline__ f32x4 process4(f32x4 o, f32x4 t,
                                          const float* __restrict__ coeffs) {
    f32x4 r;
#pragma unroll
    for (int j = 0; j < 4; ++j) {
        const float x = fminf(fmaxf(o[j], kClipLo), kClipHi);
        float rv = x;  // targets == 0 path: out = cosine
        if (t[j] != 0.0f) {
            // rare path: ~1 element per 8192
            const float phi = (x > kTH) ? clenshaw_phi(x, coeffs) : (x - kMM);
            rv = t[j] * phi + (1.0f - t[j]) * x;
        }
        r[j] = kSCALE * rv;
    }
    return r;
}

// One shot per thread: kPerThread coalesced float4 per array, stride-256
// within the block. o/t loads interleaved pairwise so compute u needs only
// the first 2(u+1) loads (incremental vmcnt), while 16 loads stay in flight.
__global__ __launch_bounds__(256) void cheb_aam_kernel(
    const f32x4* __restrict__ outputs4,
    const f32x4* __restrict__ targets4,
    const float* __restrict__ coeffs,
    f32x4*       __restrict__ dst4,
    int n4) {
    const int base = blockIdx.x * (256 * kPerThread) + threadIdx.x;

    if (base + 256 * (kPerThread - 1) < n4) {  // uniform fast path
        f32x4 o[kPerThread], t[kPerThread];
#pragma unroll
        for (int u = 0; u < kPerThread; ++u) {
            o[u] = outputs4[base + 256 * u];
            t[u] = targets4[base + 256 * u];
        }
#pragma unroll
        for (int u = 0; u < kPerThread; ++u) {
            dst4[base + 256 * u] = process4(o[u], t[u], coeffs);
        }
    } else {  // tail block (not taken for 8192x8192)
#pragma unroll
        for (int u = 0; u < kPerThread; ++u) {
            const int i = base + 256 * u;
            if (i < n4) dst4[i] = process4(outputs4[i], targets4[i], coeffs);
        }
    }
}

}  // namespace

extern "C" void kernel_launch(void* const* d_in, const int* in_sizes, int n_in,
                              void* d_out, int out_size, void* d_ws, size_t ws_size,
                              hipStream_t stream) {
    const float* outputs = (const float*)d_in[0];
    const float* targets = (const float*)d_in[1];
    const float* coeffs  = (const float*)d_in[2];
    float* dst = (float*)d_out;

    const int n  = out_size;       // 8192*8192, divisible by 4
    const int n4 = n / 4;

    const int block = 256;
    const int perBlock = block * kPerThread;           // 2048 float4 / block
    const int grid = (n4 + perBlock - 1) / perBlock;   // 8192 for 8192^2

    cheb_aam_kernel<<<grid, block, 0, stream>>>(
        (const f32x4*)outputs, (const f32x4*)targets, coeffs,
        (f32x4*)dst, n4);
}